// Round 1
// baseline (598.132 us; speedup 1.0000x reference)
//
#include <hip/hip_runtime.h>
#include <stdint.h>

typedef __bf16 bf16;
typedef __attribute__((ext_vector_type(8))) __bf16 bf16x8;
typedef __attribute__((ext_vector_type(4))) float f32x4;

static constexpr int Bn = 2, Ln = 2048, DIMn = 2048, Hn = 32, KVn = 8, HDn = 64;

// ---------------- cast fp32 -> bf16 ----------------
__global__ void cast_f32_bf16(const float* __restrict__ in, bf16* __restrict__ out, int n) {
    int i = (blockIdx.x * blockDim.x + threadIdx.x) * 4;
    if (i >= n) return;
    float4 v = *(const float4*)(in + i);
    bf16 o[4] = {(bf16)v.x, (bf16)v.y, (bf16)v.z, (bf16)v.w};
    *(uint64_t*)(out + i) = *(uint64_t*)o;
}

// ---------------- RoPE in-place on bf16, layout [B, L, nh, 64] ----------------
__global__ void rope_inplace(bf16* __restrict__ q, const float* __restrict__ fc,
                             int nheads, int total) {
    int idx = blockIdx.x * blockDim.x + threadIdx.x;
    if (idx >= total) return;
    int i  = idx & 31;
    int h  = (idx >> 5) % nheads;
    int bl = idx / (32 * nheads);     // b*L + l
    int l  = bl & (Ln - 1);
    size_t base = ((size_t)bl * nheads + h) * 64 + 2 * i;
    float cr = fc[l * 32 + i];
    float sr = fc[Ln * 32 + l * 32 + i];
    float x0 = (float)q[base], x1 = (float)q[base + 1];
    q[base]     = (bf16)(x0 * cr - x1 * sr);
    q[base + 1] = (bf16)(x0 * sr + x1 * cr);
}

// ---------------- GEMM: C[M,N] = A[M,K] * B[N,K]^T  (bf16 in, fp32 acc) ----------------
// 128x128 tile, BK=32, 256 threads = 4 waves, each wave 64x64 (4x4 MFMA 16x16x32)
template <bool OUT_BF16>
__global__ __launch_bounds__(256) void gemm_bt(const bf16* __restrict__ A,
                                               const bf16* __restrict__ Bm,
                                               void* __restrict__ C,
                                               int M, int N, int K) {
    constexpr int LDA = 40;  // padded LDS stride (elements)
    __shared__ bf16 sA[128 * LDA];
    __shared__ bf16 sB[128 * LDA];
    const int t    = threadIdx.x;
    const int wave = t >> 6, lane = t & 63;
    const int q4 = lane >> 4, l16 = lane & 15;
    const int bm = blockIdx.y * 128, bn = blockIdx.x * 128;
    const int wm = (wave >> 1) * 64, wn = (wave & 1) * 64;

    f32x4 acc[4][4] = {};

    const int srow = t >> 2;          // 0..63
    const int scol = (t & 3) * 8;     // elem col: 0,8,16,24

    for (int k0 = 0; k0 < K; k0 += 32) {
#pragma unroll
        for (int p = 0; p < 2; ++p) {
            int row = srow + p * 64;
            *(float4*)(&sA[row * LDA + scol]) =
                *(const float4*)(&A[(size_t)(bm + row) * K + k0 + scol]);
            *(float4*)(&sB[row * LDA + scol]) =
                *(const float4*)(&Bm[(size_t)(bn + row) * K + k0 + scol]);
        }
        __syncthreads();
        bf16x8 af[4], bfr[4];
#pragma unroll
        for (int i = 0; i < 4; ++i) {
            af[i]  = *(const bf16x8*)(&sA[(wm + i * 16 + l16) * LDA + q4 * 8]);
            bfr[i] = *(const bf16x8*)(&sB[(wn + i * 16 + l16) * LDA + q4 * 8]);
        }
#pragma unroll
        for (int mi = 0; mi < 4; ++mi)
#pragma unroll
            for (int ni = 0; ni < 4; ++ni)
                acc[mi][ni] = __builtin_amdgcn_mfma_f32_16x16x32_bf16(af[mi], bfr[ni],
                                                                      acc[mi][ni], 0, 0, 0);
        __syncthreads();
    }

#pragma unroll
    for (int mi = 0; mi < 4; ++mi)
#pragma unroll
        for (int ni = 0; ni < 4; ++ni)
#pragma unroll
            for (int r = 0; r < 4; ++r) {
                size_t row = bm + wm + mi * 16 + q4 * 4 + r;
                size_t col = bn + wn + ni * 16 + l16;
                if (OUT_BF16)
                    ((bf16*)C)[row * N + col] = (bf16)acc[mi][ni][r];
                else
                    ((float*)C)[row * N + col] = acc[mi][ni][r];
            }
}

// ---------------- flash attention ----------------
// Q: [B,L,H,64] bf16 (roped), K: [B,L,KV,64] bf16 (roped), V: [B,L,KV,64] bf16
// O: [B,L,H,64] bf16.  One block = (b, h, 64 q rows); 4 waves, 16 q rows each.
__global__ __launch_bounds__(256) void attn_kernel(const bf16* __restrict__ Q,
                                                   const bf16* __restrict__ Kp,
                                                   const bf16* __restrict__ Vp,
                                                   bf16* __restrict__ O) {
    constexpr int LDK = 72;  // padded LDS stride
    __shared__ bf16 sK[64 * LDK];        // [key][hd]
    __shared__ bf16 sV[64 * LDK];        // transposed: [hd][key]
    __shared__ bf16 sP[4][16 * LDK];     // per-wave P buffer [qrow][key]
    const int t    = threadIdx.x;
    const int wave = t >> 6, lane = t & 63;
    const int q4 = lane >> 4, l16 = lane & 15;
    const int qt = blockIdx.x, h = blockIdx.y, b = blockIdx.z;
    const int kvh = h >> 2;  // N_REP = 4

    // Q fragments for this wave's 16 rows (A-layout: m=l16, k=q4*8+j)
    bf16x8 qf[2];
    {
        int qrow = qt * 64 + wave * 16 + l16;
        const bf16* qp = Q + (((size_t)b * Ln + qrow) * Hn + h) * 64;
        qf[0] = *(const bf16x8*)(qp + q4 * 8);
        qf[1] = *(const bf16x8*)(qp + 32 + q4 * 8);
    }

    f32x4 o_acc[4] = {};
    float m_r[4], l_r[4];
#pragma unroll
    for (int r = 0; r < 4; ++r) { m_r[r] = -__builtin_inff(); l_r[r] = 0.f; }

    const int ntiles = qt + 1;
    for (int kt = 0; kt < ntiles; ++kt) {
        // stage K tile -> sK [key][hd]
#pragma unroll
        for (int p = 0; p < 2; ++p) {
            int f = p * 256 + t;
            int row = f >> 3, c8 = (f & 7) * 8;
            *(float4*)(&sK[row * LDK + c8]) =
                *(const float4*)(&Kp[(((size_t)b * Ln + kt * 64 + row) * KVn + kvh) * 64 + c8]);
        }
        // stage V tile transposed -> sV [hd][key]
        {
            int key = t & 63, hd0 = (t >> 6) * 16;
            const bf16* vp = &Vp[(((size_t)b * Ln + kt * 64 + key) * KVn + kvh) * 64 + hd0];
            bf16 vv[16];
            *(bf16x8*)(vv)     = *(const bf16x8*)(vp);
            *(bf16x8*)(vv + 8) = *(const bf16x8*)(vp + 8);
#pragma unroll
            for (int j = 0; j < 16; ++j) sV[(hd0 + j) * LDK + key] = vv[j];
        }
        __syncthreads();

        // S = Q K^T : 4 chunks of 16 keys
        f32x4 s[4];
#pragma unroll
        for (int c = 0; c < 4; ++c) {
            f32x4 a = {};
#pragma unroll
            for (int hc = 0; hc < 2; ++hc) {
                bf16x8 kf = *(const bf16x8*)(&sK[(c * 16 + l16) * LDK + hc * 32 + q4 * 8]);
                a = __builtin_amdgcn_mfma_f32_16x16x32_bf16(qf[hc], kf, a, 0, 0, 0);
            }
            s[c] = a;
        }

        const bool need_mask = (kt == qt);
        float mnew[4];
#pragma unroll
        for (int r = 0; r < 4; ++r) mnew[r] = m_r[r];
#pragma unroll
        for (int c = 0; c < 4; ++c)
#pragma unroll
            for (int r = 0; r < 4; ++r) {
                float v = s[c][r] * 0.125f;
                if (need_mask) {
                    int key = kt * 64 + c * 16 + l16;
                    int qr  = qt * 64 + wave * 16 + q4 * 4 + r;
                    if (key > qr) v = -__builtin_inff();
                }
                s[c][r] = v;
                mnew[r] = fmaxf(mnew[r], v);
            }
#pragma unroll
        for (int d = 1; d < 16; d <<= 1)
#pragma unroll
            for (int r = 0; r < 4; ++r)
                mnew[r] = fmaxf(mnew[r], __shfl_xor(mnew[r], d, 64));

        float alpha[4], rs[4];
#pragma unroll
        for (int r = 0; r < 4; ++r) {
            alpha[r] = __expf(m_r[r] - mnew[r]);
            m_r[r]   = mnew[r];
            rs[r]    = 0.f;
        }
        // P = exp(S - m), stash to per-wave LDS (C-layout -> row-major)
#pragma unroll
        for (int c = 0; c < 4; ++c)
#pragma unroll
            for (int r = 0; r < 4; ++r) {
                float p = __expf(s[c][r] - mnew[r]);
                rs[r] += p;
                sP[wave][(q4 * 4 + r) * LDK + c * 16 + l16] = (bf16)p;
            }
#pragma unroll
        for (int d = 1; d < 16; d <<= 1)
#pragma unroll
            for (int r = 0; r < 4; ++r)
                rs[r] += __shfl_xor(rs[r], d, 64);
#pragma unroll
        for (int r = 0; r < 4; ++r) l_r[r] = l_r[r] * alpha[r] + rs[r];
#pragma unroll
        for (int nc = 0; nc < 4; ++nc)
#pragma unroll
            for (int r = 0; r < 4; ++r) o_acc[nc][r] *= alpha[r];

        // drain own ds_writes before re-reading sP (cross-lane within wave)
        asm volatile("s_waitcnt lgkmcnt(0)" ::: "memory");

        // O += P V  (A = P rows, B = V via transposed sV)
        bf16x8 pf[2];
#pragma unroll
        for (int kc = 0; kc < 2; ++kc)
            pf[kc] = *(const bf16x8*)(&sP[wave][l16 * LDK + kc * 32 + q4 * 8]);
#pragma unroll
        for (int nc = 0; nc < 4; ++nc)
#pragma unroll
            for (int kc = 0; kc < 2; ++kc) {
                bf16x8 vf = *(const bf16x8*)(&sV[(nc * 16 + l16) * LDK + kc * 32 + q4 * 8]);
                o_acc[nc] = __builtin_amdgcn_mfma_f32_16x16x32_bf16(pf[kc], vf, o_acc[nc], 0, 0, 0);
            }
        __syncthreads();
    }

    // epilogue: normalize, store bf16 [B,L,H,64]
#pragma unroll
    for (int nc = 0; nc < 4; ++nc)
#pragma unroll
        for (int r = 0; r < 4; ++r) {
            int qr = qt * 64 + wave * 16 + q4 * 4 + r;
            int hd = nc * 16 + l16;
            O[(((size_t)b * Ln + qr) * Hn + h) * 64 + hd] = (bf16)(o_acc[nc][r] / l_r[r]);
        }
}

// ---------------- launch ----------------
extern "C" void kernel_launch(void* const* d_in, const int* in_sizes, int n_in,
                              void* d_out, int out_size, void* d_ws, size_t ws_size,
                              hipStream_t stream) {
    const float* x  = (const float*)d_in[0];
    const float* fc = (const float*)d_in[1];
    const float* wq = (const float*)d_in[2];
    const float* wk = (const float*)d_in[3];
    const float* wv = (const float*)d_in[4];
    const float* wo = (const float*)d_in[5];
    float* out = (float*)d_out;

    const size_t T = (size_t)Bn * Ln;  // 4096 tokens
    char* p = (char*)d_ws;
    bf16* xb  = (bf16*)p; p += T * DIMn * 2;
    bf16* wqb = (bf16*)p; p += (size_t)Hn * HDn * DIMn * 2;
    bf16* wkb = (bf16*)p; p += (size_t)KVn * HDn * DIMn * 2;
    bf16* wvb = (bf16*)p; p += (size_t)KVn * HDn * DIMn * 2;
    bf16* wob = (bf16*)p; p += (size_t)DIMn * Hn * HDn * 2;
    bf16* q   = (bf16*)p; p += T * Hn * HDn * 2;
    bf16* k   = (bf16*)p; p += T * KVn * HDn * 2;
    bf16* v   = (bf16*)p; p += T * KVn * HDn * 2;
    bf16* ao  = (bf16*)p; p += T * Hn * HDn * 2;

    auto cast = [&](const float* src, bf16* dst, size_t n) {
        cast_f32_bf16<<<dim3((n / 4 + 255) / 256), dim3(256), 0, stream>>>(src, dst, (int)n);
    };
    cast(x,  xb,  T * DIMn);
    cast(wq, wqb, (size_t)Hn * HDn * DIMn);
    cast(wk, wkb, (size_t)KVn * HDn * DIMn);
    cast(wv, wvb, (size_t)KVn * HDn * DIMn);
    cast(wo, wob, (size_t)DIMn * Hn * HDn);

    gemm_bt<true><<<dim3(16, 32), dim3(256), 0, stream>>>(xb, wqb, q, 4096, 2048, 2048);
    gemm_bt<true><<<dim3(4, 32),  dim3(256), 0, stream>>>(xb, wkb, k, 4096, 512, 2048);
    gemm_bt<true><<<dim3(4, 32),  dim3(256), 0, stream>>>(xb, wvb, v, 4096, 512, 2048);

    {
        int totq = Bn * Ln * Hn * 32;
        rope_inplace<<<dim3((totq + 255) / 256), dim3(256), 0, stream>>>(q, fc, Hn, totq);
        int totk = Bn * Ln * KVn * 32;
        rope_inplace<<<dim3((totk + 255) / 256), dim3(256), 0, stream>>>(k, fc, KVn, totk);
    }

    attn_kernel<<<dim3(Ln / 64, Hn, Bn), dim3(256), 0, stream>>>(q, k, v, ao);

    gemm_bt<false><<<dim3(16, 32), dim3(256), 0, stream>>>(ao, wob, out, 4096, 2048, 2048);
}

// Round 2
// 506.911 us; speedup vs baseline: 1.1800x; 1.1800x over previous
//
#include <hip/hip_runtime.h>
#include <stdint.h>

typedef __bf16 bf16;
typedef __attribute__((ext_vector_type(8))) __bf16 bf16x8;
typedef __attribute__((ext_vector_type(4))) __bf16 bf16x4;
typedef __attribute__((ext_vector_type(4))) short short4v;
typedef __attribute__((ext_vector_type(4))) float f32x4;

static constexpr int Bn = 2, Ln = 2048, DIMn = 2048, Hn = 32, KVn = 8, HDn = 64;

// ---------------- cast fp32 -> bf16 ----------------
__global__ void cast_f32_bf16(const float* __restrict__ in, bf16* __restrict__ out, int n) {
    int i = (blockIdx.x * blockDim.x + threadIdx.x) * 4;
    if (i >= n) return;
    float4 v = *(const float4*)(in + i);
    bf16 o[4] = {(bf16)v.x, (bf16)v.y, (bf16)v.z, (bf16)v.w};
    *(uint64_t*)(out + i) = *(uint64_t*)o;
}

// ---------------- RoPE in-place on bf16, layout [B, L, nh, 64] ----------------
__global__ void rope_inplace(bf16* __restrict__ q, const float* __restrict__ fc,
                             int nheads, int total) {
    int idx = blockIdx.x * blockDim.x + threadIdx.x;
    if (idx >= total) return;
    int i  = idx & 31;
    int h  = (idx >> 5) % nheads;
    int bl = idx / (32 * nheads);     // b*L + l
    int l  = bl & (Ln - 1);
    size_t base = ((size_t)bl * nheads + h) * 64 + 2 * i;
    float cr = fc[l * 32 + i];
    float sr = fc[Ln * 32 + l * 32 + i];
    float x0 = (float)q[base], x1 = (float)q[base + 1];
    q[base]     = (bf16)(x0 * cr - x1 * sr);
    q[base + 1] = (bf16)(x0 * sr + x1 * cr);
}

// ---------------- GEMM: C[M,N] = A[M,K] * B[N,K]^T  (bf16 in, fp32 acc) ----------------
// 128x128 tile, BK=32, 256 threads = 4 waves, each wave 64x64 (4x4 MFMA 16x16x32)
template <bool OUT_BF16>
__global__ __launch_bounds__(256) void gemm_bt(const bf16* __restrict__ A,
                                               const bf16* __restrict__ Bm,
                                               void* __restrict__ C,
                                               int M, int N, int K) {
    constexpr int LDA = 40;  // padded LDS stride (elements)
    __shared__ bf16 sA[128 * LDA];
    __shared__ bf16 sB[128 * LDA];
    const int t    = threadIdx.x;
    const int wave = t >> 6, lane = t & 63;
    const int q4 = lane >> 4, l16 = lane & 15;
    const int bm = blockIdx.y * 128, bn = blockIdx.x * 128;
    const int wm = (wave >> 1) * 64, wn = (wave & 1) * 64;

    f32x4 acc[4][4] = {};

    const int srow = t >> 2;          // 0..63
    const int scol = (t & 3) * 8;     // elem col: 0,8,16,24

    for (int k0 = 0; k0 < K; k0 += 32) {
#pragma unroll
        for (int p = 0; p < 2; ++p) {
            int row = srow + p * 64;
            *(float4*)(&sA[row * LDA + scol]) =
                *(const float4*)(&A[(size_t)(bm + row) * K + k0 + scol]);
            *(float4*)(&sB[row * LDA + scol]) =
                *(const float4*)(&Bm[(size_t)(bn + row) * K + k0 + scol]);
        }
        __syncthreads();
        bf16x8 af[4], bfr[4];
#pragma unroll
        for (int i = 0; i < 4; ++i) {
            af[i]  = *(const bf16x8*)(&sA[(wm + i * 16 + l16) * LDA + q4 * 8]);
            bfr[i] = *(const bf16x8*)(&sB[(wn + i * 16 + l16) * LDA + q4 * 8]);
        }
#pragma unroll
        for (int mi = 0; mi < 4; ++mi)
#pragma unroll
            for (int ni = 0; ni < 4; ++ni)
                acc[mi][ni] = __builtin_amdgcn_mfma_f32_16x16x32_bf16(af[mi], bfr[ni],
                                                                      acc[mi][ni], 0, 0, 0);
        __syncthreads();
    }

#pragma unroll
    for (int mi = 0; mi < 4; ++mi)
#pragma unroll
        for (int ni = 0; ni < 4; ++ni)
#pragma unroll
            for (int r = 0; r < 4; ++r) {
                size_t row = bm + wm + mi * 16 + q4 * 4 + r;
                size_t col = bn + wn + ni * 16 + l16;
                if (OUT_BF16)
                    ((bf16*)C)[row * N + col] = (bf16)acc[mi][ni][r];
                else
                    ((float*)C)[row * N + col] = acc[mi][ni][r];
            }
}

// ---------------- flash attention (S^T formulation) ----------------
// Q: [B,L,H,64] bf16 (roped), K: [B,L,KV,64] bf16 (roped), V: [B,L,KV,64] bf16
// O: [B,L,H,64] bf16.  One block = (b, h, 64 q rows); 4 waves, 16 q rows each.
// S^T = K.Q^T via mfma(A=K,B=Q): C-layout lane(q4,l16) holds S^T[key=16c+4q4+r][q=l16]
//  -> softmax is per-lane over 16 regs + 2 shuffles (xor16, xor32).
// P^T in C-layout IS the B-operand layout of mfma_f32_16x16x16bf16_1k (k=4q4+r,n=l16),
//  so PV = V^T.P^T runs with NO LDS round-trip for P. O^T epilogue: hd=nc*16+4q4+r, q=l16.
__global__ __launch_bounds__(256) void attn_kernel(const bf16* __restrict__ Q,
                                                   const bf16* __restrict__ Kp,
                                                   const bf16* __restrict__ Vp,
                                                   bf16* __restrict__ O) {
    constexpr int LDK = 72;  // padded LDS stride
    __shared__ bf16 sK[64 * LDK];        // [key][hd]
    __shared__ bf16 sV[64 * LDK];        // transposed: [hd][key]
    const int t    = threadIdx.x;
    const int wave = t >> 6, lane = t & 63;
    const int q4 = lane >> 4, l16 = lane & 15;
    const int qt = (gridDim.x - 1) - blockIdx.x;   // heavy blocks first
    const int h = blockIdx.y, b = blockIdx.z;
    const int kvh = h >> 2;  // N_REP = 4

    // Q fragment as B-operand: n=l16 -> q row, k=8*q4+j -> hd
    const int qrow = qt * 64 + wave * 16 + l16;
    const bf16* qp = Q + (((size_t)b * Ln + qrow) * Hn + h) * 64;
    bf16x8 qf[2];
    qf[0] = *(const bf16x8*)(qp + q4 * 8);
    qf[1] = *(const bf16x8*)(qp + 32 + q4 * 8);

    f32x4 o_acc[4] = {};
    float m_r = -__builtin_inff(), l_r = 0.f;

    for (int kt = 0; kt <= qt; ++kt) {
        // stage K tile -> sK [key][hd]
#pragma unroll
        for (int p = 0; p < 2; ++p) {
            int f = p * 256 + t;
            int row = f >> 3, c8 = (f & 7) * 8;
            *(float4*)(&sK[row * LDK + c8]) =
                *(const float4*)(&Kp[(((size_t)b * Ln + kt * 64 + row) * KVn + kvh) * 64 + c8]);
        }
        // stage V tile transposed -> sV [hd][key]
        {
            int key = t & 63, hd0 = (t >> 6) * 16;
            const bf16* vp = &Vp[(((size_t)b * Ln + kt * 64 + key) * KVn + kvh) * 64 + hd0];
            bf16 vv[16];
            *(bf16x8*)(vv)     = *(const bf16x8*)(vp);
            *(bf16x8*)(vv + 8) = *(const bf16x8*)(vp + 8);
#pragma unroll
            for (int j = 0; j < 16; ++j) sV[(hd0 + j) * LDK + key] = vv[j];
        }
        __syncthreads();

        // S^T = K Q^T : 4 chunks of 16 keys
        f32x4 s[4];
#pragma unroll
        for (int c = 0; c < 4; ++c) {
            f32x4 a = {};
#pragma unroll
            for (int hc = 0; hc < 2; ++hc) {
                bf16x8 kf = *(const bf16x8*)(&sK[(c * 16 + l16) * LDK + hc * 32 + q4 * 8]);
                a = __builtin_amdgcn_mfma_f32_16x16x32_bf16(kf, qf[hc], a, 0, 0, 0);
            }
            s[c] = a;
        }

        // scale + causal mask (diagonal tile only) + per-lane max
        const bool diag = (kt == qt);
        float mnew = m_r;
#pragma unroll
        for (int c = 0; c < 4; ++c)
#pragma unroll
            for (int r = 0; r < 4; ++r) {
                float v = s[c][r] * 0.125f;
                if (diag && (kt * 64 + c * 16 + q4 * 4 + r > qrow)) v = -__builtin_inff();
                s[c][r] = v;
                mnew = fmaxf(mnew, v);
            }
        mnew = fmaxf(mnew, __shfl_xor(mnew, 16, 64));
        mnew = fmaxf(mnew, __shfl_xor(mnew, 32, 64));

        float alpha = __expf(m_r - mnew);
        m_r = mnew;
        float rs = 0.f;
        short4v pb[4];
#pragma unroll
        for (int c = 0; c < 4; ++c)
#pragma unroll
            for (int r = 0; r < 4; ++r) {
                float p = __expf(s[c][r] - mnew);
                rs += p;
                bf16 ph = (bf16)p;
                pb[c][r] = *(short*)&ph;
            }
        rs += __shfl_xor(rs, 16, 64);
        rs += __shfl_xor(rs, 32, 64);
        l_r = l_r * alpha + rs;
#pragma unroll
        for (int nc = 0; nc < 4; ++nc)
#pragma unroll
            for (int r = 0; r < 4; ++r) o_acc[nc][r] *= alpha;

        // O^T += V^T P^T : A = V^T frag (m=hd, k=key chunk), B = P^T (in-register!)
#pragma unroll
        for (int nc = 0; nc < 4; ++nc)
#pragma unroll
            for (int c = 0; c < 4; ++c) {
                short4v vf = *(const short4v*)(&sV[(nc * 16 + l16) * LDK + c * 16 + q4 * 4]);
                o_acc[nc] = __builtin_amdgcn_mfma_f32_16x16x16bf16_1k(vf, pb[c], o_acc[nc], 0, 0, 0);
            }
        __syncthreads();
    }

    // epilogue: O^T layout -> store bf16 [B,L,H,64]; q=l16, hd=nc*16+4q4+r
    float inv = 1.f / l_r;
    bf16* op = O + (((size_t)b * Ln + qrow) * Hn + h) * 64;
#pragma unroll
    for (int nc = 0; nc < 4; ++nc) {
        bf16x4 o;
#pragma unroll
        for (int r = 0; r < 4; ++r) o[r] = (bf16)(o_acc[nc][r] * inv);
        *(bf16x4*)(op + nc * 16 + q4 * 4) = o;
    }
}

// ---------------- launch ----------------
extern "C" void kernel_launch(void* const* d_in, const int* in_sizes, int n_in,
                              void* d_out, int out_size, void* d_ws, size_t ws_size,
                              hipStream_t stream) {
    const float* x  = (const float*)d_in[0];
    const float* fc = (const float*)d_in[1];
    const float* wq = (const float*)d_in[2];
    const float* wk = (const float*)d_in[3];
    const float* wv = (const float*)d_in[4];
    const float* wo = (const float*)d_in[5];
    float* out = (float*)d_out;

    const size_t T = (size_t)Bn * Ln;  // 4096 tokens
    char* p = (char*)d_ws;
    bf16* xb  = (bf16*)p; p += T * DIMn * 2;
    bf16* wqb = (bf16*)p; p += (size_t)Hn * HDn * DIMn * 2;
    bf16* wkb = (bf16*)p; p += (size_t)KVn * HDn * DIMn * 2;
    bf16* wvb = (bf16*)p; p += (size_t)KVn * HDn * DIMn * 2;
    bf16* wob = (bf16*)p; p += (size_t)DIMn * Hn * HDn * 2;
    bf16* q   = (bf16*)p; p += T * Hn * HDn * 2;
    bf16* k   = (bf16*)p; p += T * KVn * HDn * 2;
    bf16* v   = (bf16*)p; p += T * KVn * HDn * 2;
    bf16* ao  = (bf16*)p; p += T * Hn * HDn * 2;

    auto cast = [&](const float* src, bf16* dst, size_t n) {
        cast_f32_bf16<<<dim3((n / 4 + 255) / 256), dim3(256), 0, stream>>>(src, dst, (int)n);
    };
    cast(x,  xb,  T * DIMn);
    cast(wq, wqb, (size_t)Hn * HDn * DIMn);
    cast(wk, wkb, (size_t)KVn * HDn * DIMn);
    cast(wv, wvb, (size_t)KVn * HDn * DIMn);
    cast(wo, wob, (size_t)DIMn * Hn * HDn);

    gemm_bt<true><<<dim3(16, 32), dim3(256), 0, stream>>>(xb, wqb, q, 4096, 2048, 2048);
    gemm_bt<true><<<dim3(4, 32),  dim3(256), 0, stream>>>(xb, wkb, k, 4096, 512, 2048);
    gemm_bt<true><<<dim3(4, 32),  dim3(256), 0, stream>>>(xb, wvb, v, 4096, 512, 2048);

    {
        int totq = Bn * Ln * Hn * 32;
        rope_inplace<<<dim3((totq + 255) / 256), dim3(256), 0, stream>>>(q, fc, Hn, totq);
        int totk = Bn * Ln * KVn * 32;
        rope_inplace<<<dim3((totk + 255) / 256), dim3(256), 0, stream>>>(k, fc, KVn, totk);
    }

    attn_kernel<<<dim3(Ln / 64, Hn, Bn), dim3(256), 0, stream>>>(q, k, v, ao);

    gemm_bt<false><<<dim3(16, 32), dim3(256), 0, stream>>>(ao, wob, out, 4096, 2048, 2048);
}

// Round 3
// 425.917 us; speedup vs baseline: 1.4043x; 1.1902x over previous
//
#include <hip/hip_runtime.h>
#include <stdint.h>

typedef __bf16 bf16;
typedef __attribute__((ext_vector_type(8))) __bf16 bf16x8;
typedef __attribute__((ext_vector_type(4))) __bf16 bf16x4;
typedef __attribute__((ext_vector_type(4))) short short4v;
typedef __attribute__((ext_vector_type(4))) float f32x4;

static constexpr int Bn = 2, Ln = 2048, DIMn = 2048, Hn = 32, KVn = 8, HDn = 64;
static constexpr int TS = 3072;  // fused qkv token stride (2048 q + 512 k + 512 v)

#if defined(__has_builtin)
#if __has_builtin(__builtin_amdgcn_exp2f)
#define EXP2(x) __builtin_amdgcn_exp2f(x)
#endif
#endif
#ifndef EXP2
#define EXP2(x) exp2f(x)
#endif

#define TO_LDS(p) ((__attribute__((address_space(3))) uint32_t*)(uintptr_t)(p))
#define TO_GLB(p) ((const __attribute__((address_space(1))) uint32_t*)(uintptr_t)(p))

// ---------------- cast fp32 -> bf16 ----------------
__global__ void cast_f32_bf16(const float* __restrict__ in, bf16* __restrict__ out, int n) {
    int i = (blockIdx.x * blockDim.x + threadIdx.x) * 4;
    if (i >= n) return;
    float4 v = *(const float4*)(in + i);
    bf16 o[4] = {(bf16)v.x, (bf16)v.y, (bf16)v.z, (bf16)v.w};
    *(uint64_t*)(out + i) = *(uint64_t*)o;
}

// ---------------- RoPE in-place on fused qkv [T, 3072]: q cols 0..2047, k cols 2048..2559 ----
__global__ void rope_qk(bf16* __restrict__ qkv, const float* __restrict__ fc, int total) {
    int idx = blockIdx.x * blockDim.x + threadIdx.x;
    if (idx >= total) return;
    int i  = idx & 31;            // freq index
    int hj = (idx >> 5) % 40;     // 0..31 q heads, 32..39 k heads (col hj*64 works for both)
    int bl = idx / (32 * 40);     // b*L + l
    int l  = bl & (Ln - 1);
    size_t base = (size_t)bl * TS + hj * 64 + 2 * i;
    float cr = fc[l * 32 + i];
    float sr = fc[Ln * 32 + l * 32 + i];
    float x0 = (float)qkv[base], x1 = (float)qkv[base + 1];
    qkv[base]     = (bf16)(x0 * cr - x1 * sr);
    qkv[base + 1] = (bf16)(x0 * sr + x1 * cr);
}

// ---------------- GEMM: C[M,N] = A[M,K] * B[N,K]^T  (bf16 in, fp32 acc) ----------------
// m97 structure: 128x128 tile, BK=32, global_load_lds dwordx4 into unpadded stride-32 LDS.
template <bool OUT_BF16>
__global__ __launch_bounds__(256) void gemm_bt(const bf16* __restrict__ A,
                                               const bf16* __restrict__ Bm,
                                               void* __restrict__ C,
                                               int M, int N, int K) {
    __shared__ bf16 sA[128 * 32];
    __shared__ bf16 sB[128 * 32];
    const int t    = threadIdx.x;
    const int wave = t >> 6, lane = t & 63;
    const int q4 = lane >> 4, l16 = lane & 15;
    const int bm = blockIdx.y * 128, bn = blockIdx.x * 128;
    const int wm = (wave >> 1) * 64, wn = (wave & 1) * 64;

    f32x4 acc[4][4] = {};

    // staging: issue p covers rows p*64 + wave*16 .. +16; lane l -> row +l/4, col (l&3)*8
    const int srow = wave * 16 + (lane >> 2);
    const int scol = (lane & 3) * 8;
    const bf16* pa = A + (size_t)(bm + srow) * K + scol;
    const bf16* pb = Bm + (size_t)(bn + srow) * K + scol;
    bf16* la = &sA[wave * 16 * 32];   // wave-uniform LDS base; HW adds lane*16B
    bf16* lb = &sB[wave * 16 * 32];

    for (int k0 = 0; k0 < K; k0 += 32) {
#pragma unroll
        for (int p = 0; p < 2; ++p) {
            __builtin_amdgcn_global_load_lds(TO_GLB(pa + (size_t)p * 64 * K),
                                             TO_LDS(la + p * 64 * 32), 16, 0, 0);
            __builtin_amdgcn_global_load_lds(TO_GLB(pb + (size_t)p * 64 * K),
                                             TO_LDS(lb + p * 64 * 32), 16, 0, 0);
        }
        pa += 32; pb += 32;
        __syncthreads();
        bf16x8 af[4], bfr[4];
#pragma unroll
        for (int i = 0; i < 4; ++i) {
            af[i]  = *(const bf16x8*)(&sA[(wm + i * 16 + l16) * 32 + q4 * 8]);
            bfr[i] = *(const bf16x8*)(&sB[(wn + i * 16 + l16) * 32 + q4 * 8]);
        }
#pragma unroll
        for (int mi = 0; mi < 4; ++mi)
#pragma unroll
            for (int ni = 0; ni < 4; ++ni)
                acc[mi][ni] = __builtin_amdgcn_mfma_f32_16x16x32_bf16(af[mi], bfr[ni],
                                                                      acc[mi][ni], 0, 0, 0);
        __syncthreads();
    }

#pragma unroll
    for (int mi = 0; mi < 4; ++mi)
#pragma unroll
        for (int ni = 0; ni < 4; ++ni)
#pragma unroll
            for (int r = 0; r < 4; ++r) {
                size_t row = bm + wm + mi * 16 + q4 * 4 + r;
                size_t col = bn + wn + ni * 16 + l16;
                if (OUT_BF16)
                    ((bf16*)C)[row * N + col] = (bf16)acc[mi][ni][r];
                else
                    ((float*)C)[row * N + col] = acc[mi][ni][r];
            }
}

// ---------------- flash attention (S^T formulation, fused qkv input) ----------------
// qkv: [B,L,3072] bf16 (roped). One block = (b, h, 64 q rows); 4 waves, 16 q rows each.
// S^T = K.Q^T; P^T stays in registers (C-layout == B-operand of 16x16x16bf16_1k).
__global__ __launch_bounds__(256) void attn_kernel(const bf16* __restrict__ QKV,
                                                   bf16* __restrict__ O) {
    constexpr int LDK = 72;
    __shared__ bf16 sK[64 * LDK];        // [key][hd]
    __shared__ bf16 sV[64 * LDK];        // transposed: [hd][key]
    const int t    = threadIdx.x;
    const int wave = t >> 6, lane = t & 63;
    const int q4 = lane >> 4, l16 = lane & 15;
    const int qt = (gridDim.x - 1) - blockIdx.x;   // heavy blocks first
    const int h = blockIdx.y, b = blockIdx.z;
    const int kvh = h >> 2;  // N_REP = 4

    // Q fragment as B-operand: n=l16 -> q row, k=8*q4+j -> hd
    const int qrow = qt * 64 + wave * 16 + l16;
    const bf16* qp = QKV + (size_t)(b * Ln + qrow) * TS + h * 64;
    bf16x8 qf[2];
    qf[0] = *(const bf16x8*)(qp + q4 * 8);
    qf[1] = *(const bf16x8*)(qp + 32 + q4 * 8);

    // staging bases
    const bf16* kb = QKV + (size_t)(b * Ln) * TS + 2048 + kvh * 64;
    const bf16* vb = kb + 512;
    const int krow = t >> 3;           // K stage: row within 32-row half
    const int kc8  = (t & 7) * 8;
    const int vkey = t & 63, vhd0 = (t >> 6) * 16;

    f32x4 o_acc[4] = {};
    float m_r = -__builtin_inff(), l_r = 0.f;
    constexpr float SC = 0.125f * 1.44269504088896340736f;  // scale * log2(e)

    for (int kt = 0; kt <= qt; ++kt) {
        const bf16* kp = kb + (size_t)kt * 64 * TS;
        const bf16* vp = vb + (size_t)kt * 64 * TS;
        // stage K tile -> sK [key][hd]
#pragma unroll
        for (int p = 0; p < 2; ++p) {
            int row = p * 32 + krow;
            *(float4*)(&sK[row * LDK + kc8]) = *(const float4*)(&kp[(size_t)row * TS + kc8]);
        }
        // stage V tile transposed -> sV [hd][key]
        {
            const bf16* v0 = &vp[(size_t)vkey * TS + vhd0];
            bf16 vv[16];
            *(bf16x8*)(vv)     = *(const bf16x8*)(v0);
            *(bf16x8*)(vv + 8) = *(const bf16x8*)(v0 + 8);
#pragma unroll
            for (int j = 0; j < 16; ++j) sV[(vhd0 + j) * LDK + vkey] = vv[j];
        }
        __syncthreads();

        // S^T = K Q^T : 4 chunks of 16 keys
        f32x4 s[4];
#pragma unroll
        for (int c = 0; c < 4; ++c) {
            f32x4 a = {};
#pragma unroll
            for (int hc = 0; hc < 2; ++hc) {
                bf16x8 kf = *(const bf16x8*)(&sK[(c * 16 + l16) * LDK + hc * 32 + q4 * 8]);
                a = __builtin_amdgcn_mfma_f32_16x16x32_bf16(kf, qf[hc], a, 0, 0, 0);
            }
            s[c] = a;
        }

        // scale into log2 domain (+ causal mask on diagonal tile only), per-lane max
        float mnew = m_r;
        if (kt == qt) {
#pragma unroll
            for (int c = 0; c < 4; ++c)
#pragma unroll
                for (int r = 0; r < 4; ++r) {
                    float v = s[c][r] * SC;
                    if (kt * 64 + c * 16 + q4 * 4 + r > qrow) v = -__builtin_inff();
                    s[c][r] = v;
                    mnew = fmaxf(mnew, v);
                }
        } else {
#pragma unroll
            for (int c = 0; c < 4; ++c)
#pragma unroll
                for (int r = 0; r < 4; ++r) {
                    float v = s[c][r] * SC;
                    s[c][r] = v;
                    mnew = fmaxf(mnew, v);
                }
        }
        mnew = fmaxf(mnew, __shfl_xor(mnew, 16, 64));
        mnew = fmaxf(mnew, __shfl_xor(mnew, 32, 64));

        float alpha = EXP2(m_r - mnew);
        m_r = mnew;
        float rs = 0.f;
        short4v pb4[4];
#pragma unroll
        for (int c = 0; c < 4; ++c)
#pragma unroll
            for (int r = 0; r < 4; ++r) {
                float p = EXP2(s[c][r] - mnew);
                rs += p;
                bf16 ph = (bf16)p;
                pb4[c][r] = *(short*)&ph;
            }
        rs += __shfl_xor(rs, 16, 64);
        rs += __shfl_xor(rs, 32, 64);
        l_r = l_r * alpha + rs;
#pragma unroll
        for (int nc = 0; nc < 4; ++nc)
#pragma unroll
            for (int r = 0; r < 4; ++r) o_acc[nc][r] *= alpha;

        // O^T += V^T P^T : A = V^T frag from sV, B = P^T in registers
#pragma unroll
        for (int nc = 0; nc < 4; ++nc)
#pragma unroll
            for (int c = 0; c < 4; ++c) {
                short4v vf = *(const short4v*)(&sV[(nc * 16 + l16) * LDK + c * 16 + q4 * 4]);
                o_acc[nc] = __builtin_amdgcn_mfma_f32_16x16x16bf16_1k(vf, pb4[c], o_acc[nc], 0, 0, 0);
            }
        __syncthreads();
    }

    // epilogue: O^T layout -> store bf16 [B,L,H,64]; q=l16, hd=nc*16+4q4+r
    float inv = 1.f / l_r;
    bf16* op = O + (size_t)(b * Ln + qrow) * (Hn * HDn) + h * 64;
#pragma unroll
    for (int nc = 0; nc < 4; ++nc) {
        bf16x4 o;
#pragma unroll
        for (int r = 0; r < 4; ++r) o[r] = (bf16)(o_acc[nc][r] * inv);
        *(bf16x4*)(op + nc * 16 + q4 * 4) = o;
    }
}

// ---------------- launch ----------------
extern "C" void kernel_launch(void* const* d_in, const int* in_sizes, int n_in,
                              void* d_out, int out_size, void* d_ws, size_t ws_size,
                              hipStream_t stream) {
    const float* x  = (const float*)d_in[0];
    const float* fc = (const float*)d_in[1];
    const float* wq = (const float*)d_in[2];
    const float* wk = (const float*)d_in[3];
    const float* wv = (const float*)d_in[4];
    const float* wo = (const float*)d_in[5];
    float* out = (float*)d_out;

    const size_t T = (size_t)Bn * Ln;  // 4096 tokens
    char* p = (char*)d_ws;
    bf16* xb    = (bf16*)p; p += T * DIMn * 2;
    bf16* wqkvb = (bf16*)p; p += (size_t)TS * DIMn * 2;   // [3072, 2048] = wq;wk;wv rows
    bf16* wob   = (bf16*)p; p += (size_t)DIMn * Hn * HDn * 2;
    bf16* qkv   = (bf16*)p; p += T * TS * 2;              // fused projections
    bf16* ao    = (bf16*)p; p += T * Hn * HDn * 2;

    auto cast = [&](const float* src, bf16* dst, size_t n) {
        cast_f32_bf16<<<dim3((n / 4 + 255) / 256), dim3(256), 0, stream>>>(src, dst, (int)n);
    };
    cast(x,  xb, T * DIMn);
    cast(wq, wqkvb,                      (size_t)2048 * 2048);
    cast(wk, wqkvb + (size_t)2048 * 2048, (size_t)512 * 2048);
    cast(wv, wqkvb + (size_t)2560 * 2048, (size_t)512 * 2048);
    cast(wo, wob,                        (size_t)2048 * 2048);

    // fused QKV projection: [4096, 3072]
    gemm_bt<true><<<dim3(TS / 128, 32), dim3(256), 0, stream>>>(xb, wqkvb, qkv, 4096, TS, 2048);

    rope_qk<<<dim3((int)(T * 1280 / 256)), dim3(256), 0, stream>>>(qkv, fc, (int)(T * 1280));

    attn_kernel<<<dim3(Ln / 64, Hn, Bn), dim3(256), 0, stream>>>(qkv, ao);

    gemm_bt<false><<<dim3(16, 32), dim3(256), 0, stream>>>(ao, wob, out, 4096, 2048, 2048);
}

// Round 4
// 327.210 us; speedup vs baseline: 1.8280x; 1.3017x over previous
//
#include <hip/hip_runtime.h>
#include <stdint.h>

typedef __bf16 bf16;
typedef __attribute__((ext_vector_type(8))) __bf16 bf16x8;
typedef __attribute__((ext_vector_type(4))) __bf16 bf16x4;
typedef __attribute__((ext_vector_type(4))) short short4v;
typedef __attribute__((ext_vector_type(4))) float f32x4;

static constexpr int Bn = 2, Ln = 2048, DIMn = 2048, Hn = 32, KVn = 8, HDn = 64;
static constexpr int TS = 3072;  // fused qkv token stride (2048 q + 512 k + 512 v)

#if defined(__has_builtin)
#if __has_builtin(__builtin_amdgcn_exp2f)
#define EXP2(x) __builtin_amdgcn_exp2f(x)
#endif
#endif
#ifndef EXP2
#define EXP2(x) exp2f(x)
#endif

#define TO_LDS(p) ((__attribute__((address_space(3))) uint32_t*)(uintptr_t)(p))
#define TO_GLB(p) ((const __attribute__((address_space(1))) uint32_t*)(uintptr_t)(p))

// ---------------- fused cast fp32 -> bf16 for all 5 inputs ----------------
// virtual concat: x[8388608] | wq[4194304] wk[1048576] wv[1048576] -> wqkvb | wo[4194304] -> wob
__global__ void cast_all(const float* __restrict__ x, const float* __restrict__ wq,
                         const float* __restrict__ wk, const float* __restrict__ wv,
                         const float* __restrict__ wo, bf16* __restrict__ xb,
                         bf16* __restrict__ wqkvb, bf16* __restrict__ wob) {
    size_t i = (size_t)(blockIdx.x * blockDim.x + threadIdx.x) * 4;
    const float* src;
    bf16* dst;
    if (i < 8388608) {
        src = x + i; dst = xb + i;
    } else if (i < 8388608 + 6291456) {
        size_t j = i - 8388608;
        dst = wqkvb + j;
        if (j < 4194304)      src = wq + j;
        else if (j < 5242880) src = wk + (j - 4194304);
        else                  src = wv + (j - 5242880);
    } else {
        size_t j = i - 14680064;
        src = wo + j; dst = wob + j;
    }
    float4 v = *(const float4*)src;
    bf16 o[4] = {(bf16)v.x, (bf16)v.y, (bf16)v.z, (bf16)v.w};
    *(uint64_t*)dst = *(uint64_t*)o;
}

// ---------------- GEMM: C[M,N] = A[M,K] * B[N,K]^T  (bf16 in, fp32 acc) ----------------
// m97 structure: 128x128 tile, BK=32, global_load_lds dwordx4 into unpadded stride-32 LDS.
template <bool OUT_BF16>
__global__ __launch_bounds__(256) void gemm_bt(const bf16* __restrict__ A,
                                               const bf16* __restrict__ Bm,
                                               void* __restrict__ C,
                                               int M, int N, int K) {
    __shared__ bf16 sA[128 * 32];
    __shared__ bf16 sB[128 * 32];
    const int t    = threadIdx.x;
    const int wave = t >> 6, lane = t & 63;
    const int q4 = lane >> 4, l16 = lane & 15;
    const int bm = blockIdx.y * 128, bn = blockIdx.x * 128;
    const int wm = (wave >> 1) * 64, wn = (wave & 1) * 64;

    f32x4 acc[4][4] = {};

    const int srow = wave * 16 + (lane >> 2);
    const int scol = (lane & 3) * 8;
    const bf16* pa = A + (size_t)(bm + srow) * K + scol;
    const bf16* pb = Bm + (size_t)(bn + srow) * K + scol;
    bf16* la = &sA[wave * 16 * 32];
    bf16* lb = &sB[wave * 16 * 32];

    for (int k0 = 0; k0 < K; k0 += 32) {
#pragma unroll
        for (int p = 0; p < 2; ++p) {
            __builtin_amdgcn_global_load_lds(TO_GLB(pa + (size_t)p * 64 * K),
                                             TO_LDS(la + p * 64 * 32), 16, 0, 0);
            __builtin_amdgcn_global_load_lds(TO_GLB(pb + (size_t)p * 64 * K),
                                             TO_LDS(lb + p * 64 * 32), 16, 0, 0);
        }
        pa += 32; pb += 32;
        __syncthreads();
        bf16x8 af[4], bfr[4];
#pragma unroll
        for (int i = 0; i < 4; ++i) {
            af[i]  = *(const bf16x8*)(&sA[(wm + i * 16 + l16) * 32 + q4 * 8]);
            bfr[i] = *(const bf16x8*)(&sB[(wn + i * 16 + l16) * 32 + q4 * 8]);
        }
#pragma unroll
        for (int mi = 0; mi < 4; ++mi)
#pragma unroll
            for (int ni = 0; ni < 4; ++ni)
                acc[mi][ni] = __builtin_amdgcn_mfma_f32_16x16x32_bf16(af[mi], bfr[ni],
                                                                      acc[mi][ni], 0, 0, 0);
        __syncthreads();
    }

#pragma unroll
    for (int mi = 0; mi < 4; ++mi)
#pragma unroll
        for (int ni = 0; ni < 4; ++ni)
#pragma unroll
            for (int r = 0; r < 4; ++r) {
                size_t row = bm + wm + mi * 16 + q4 * 4 + r;
                size_t col = bn + wn + ni * 16 + l16;
                if (OUT_BF16)
                    ((bf16*)C)[row * N + col] = (bf16)acc[mi][ni][r];
                else
                    ((float*)C)[row * N + col] = acc[mi][ni][r];
            }
}

// ---------------- flash attention: 4-head-fused, uniform q-tile pairs ----------------
// Block = (pair, kvh, b): 4 waves, wave w = head kvh*4+w, handling ALL 64 q rows.
// Processes q-tile (31-pair) then (pair): uniform 33 tile-iterations per block.
// Static-max softmax in log2 domain (scale*log2e folded into Q during in-reg RoPE):
//   p = exp2(s - 12); l accumulated per-lane, reduced once at epilogue. No per-tile shuffles.
// K-RoPE fused into K staging. K/V prefetched into registers one tile ahead.
__global__ __launch_bounds__(256, 1) void attn_kernel(const bf16* __restrict__ QKV,
                                                      const float* __restrict__ fc,
                                                      bf16* __restrict__ O) {
    constexpr int LDK = 72;
    __shared__ bf16 sK[64 * LDK];        // [key][hd] (roped)
    __shared__ bf16 sV[64 * LDK];        // transposed: [hd][key]
    const int t    = threadIdx.x;
    const int wave = t >> 6, lane = t & 63;
    const int q4 = lane >> 4, l16 = lane & 15;
    const int pair = blockIdx.x, kvh = blockIdx.y, b = blockIdx.z;
    const int h = kvh * 4 + wave;
    constexpr float SC = 0.125f * 1.44269504088896340736f;  // folded into Q

    const bf16* kb = QKV + (size_t)(b * Ln) * TS + 2048 + kvh * 64;
    const bf16* vb = kb + 512;
    // staging thread mapping
    const int krow = t >> 3;           // 0..31 (rows krow, krow+32)
    const int kc8  = (t & 7) * 8;
    const int kfrq = kc8 >> 1;
    const int vkey = t & 63, vhd0 = (t >> 6) * 16;

    for (int half = 0; half < 2; ++half) {
        const int qtile = half == 0 ? 31 - pair : pair;

        // ---- load Q fragments, RoPE + scale in-register ----
        bf16x8 qf[4][2];
#pragma unroll
        for (int g = 0; g < 4; ++g) {
            int ql = qtile * 64 + g * 16 + l16;
            const bf16* qp = QKV + (size_t)(b * Ln + ql) * TS + h * 64;
#pragma unroll
            for (int hc = 0; hc < 2; ++hc) {
                bf16x8 raw = *(const bf16x8*)(qp + hc * 32 + q4 * 8);
                float4 c4 = *(const float4*)(fc + ql * 32 + hc * 16 + q4 * 4);
                float4 s4 = *(const float4*)(fc + 65536 + ql * 32 + hc * 16 + q4 * 4);
                bf16x8 o;
#pragma unroll
                for (int m = 0; m < 4; ++m) {
                    float cr = ((const float*)&c4)[m], sr = ((const float*)&s4)[m];
                    float x0 = (float)raw[2 * m], x1 = (float)raw[2 * m + 1];
                    o[2 * m]     = (bf16)((x0 * cr - x1 * sr) * SC);
                    o[2 * m + 1] = (bf16)((x0 * sr + x1 * cr) * SC);
                }
                qf[g][hc] = o;
            }
        }

        f32x4 o_acc[4][4] = {};
        float l_r[4] = {0.f, 0.f, 0.f, 0.f};

        // ---- prefetch tile 0 into registers ----
        bf16x8 kreg[2], vreg[2];
        float4 kc4[2], ks4[2];
        {
            const bf16* kp = kb;
            const bf16* vp = vb;
#pragma unroll
            for (int p = 0; p < 2; ++p) {
                int row = p * 32 + krow;
                kreg[p] = *(const bf16x8*)(kp + (size_t)row * TS + kc8);
                kc4[p] = *(const float4*)(fc + row * 32 + kfrq);
                ks4[p] = *(const float4*)(fc + 65536 + row * 32 + kfrq);
            }
            const bf16* v0 = vp + (size_t)vkey * TS + vhd0;
            vreg[0] = *(const bf16x8*)(v0);
            vreg[1] = *(const bf16x8*)(v0 + 8);
        }

        for (int kt = 0; kt <= qtile; ++kt) {
            // ---- write staged tile to LDS (K roped here) ----
#pragma unroll
            for (int p = 0; p < 2; ++p) {
                int row = p * 32 + krow;
                bf16 out[8];
#pragma unroll
                for (int m = 0; m < 4; ++m) {
                    float cr = ((const float*)&kc4[p])[m], sr = ((const float*)&ks4[p])[m];
                    float x0 = (float)kreg[p][2 * m], x1 = (float)kreg[p][2 * m + 1];
                    out[2 * m]     = (bf16)(x0 * cr - x1 * sr);
                    out[2 * m + 1] = (bf16)(x0 * sr + x1 * cr);
                }
                *(float4*)(&sK[row * LDK + kc8]) = *(float4*)out;
            }
            {
                bf16 vv[16];
                *(bf16x8*)(vv)     = vreg[0];
                *(bf16x8*)(vv + 8) = vreg[1];
#pragma unroll
                for (int j = 0; j < 16; ++j) sV[(vhd0 + j) * LDK + vkey] = vv[j];
            }
            __syncthreads();

            // ---- prefetch next tile ----
            if (kt < qtile) {
                const bf16* kp = kb + (size_t)(kt + 1) * 64 * TS;
                const bf16* vp = vb + (size_t)(kt + 1) * 64 * TS;
#pragma unroll
                for (int p = 0; p < 2; ++p) {
                    int row = p * 32 + krow;
                    kreg[p] = *(const bf16x8*)(kp + (size_t)row * TS + kc8);
                    int l = (kt + 1) * 64 + row;
                    kc4[p] = *(const float4*)(fc + l * 32 + kfrq);
                    ks4[p] = *(const float4*)(fc + 65536 + l * 32 + kfrq);
                }
                const bf16* v0 = vp + (size_t)vkey * TS + vhd0;
                vreg[0] = *(const bf16x8*)(v0);
                vreg[1] = *(const bf16x8*)(v0 + 8);
            }

            // ---- shared fragments (reused by all 4 q-groups) ----
            bf16x8 kf[4][2];
#pragma unroll
            for (int c = 0; c < 4; ++c)
#pragma unroll
                for (int hc = 0; hc < 2; ++hc)
                    kf[c][hc] = *(const bf16x8*)(&sK[(c * 16 + l16) * LDK + hc * 32 + q4 * 8]);
            short4v vf[4][4];
#pragma unroll
            for (int nc = 0; nc < 4; ++nc)
#pragma unroll
                for (int c = 0; c < 4; ++c)
                    vf[nc][c] = *(const short4v*)(&sV[(nc * 16 + l16) * LDK + c * 16 + q4 * 4]);

            const bool diag = (kt == qtile);
#pragma unroll
            for (int g = 0; g < 4; ++g) {
                // S^T = K Q^T (scores already in log2 domain via Q scaling)
                f32x4 s[4];
#pragma unroll
                for (int c = 0; c < 4; ++c) {
                    f32x4 a = {};
                    a = __builtin_amdgcn_mfma_f32_16x16x32_bf16(kf[c][0], qf[g][0], a, 0, 0, 0);
                    a = __builtin_amdgcn_mfma_f32_16x16x32_bf16(kf[c][1], qf[g][1], a, 0, 0, 0);
                    s[c] = a;
                }
                // static-max softmax: p = exp2(s - 12)
                int qrow = qtile * 64 + g * 16 + l16;
                float lsum = 0.f;
                short4v pb4[4];
#pragma unroll
                for (int c = 0; c < 4; ++c)
#pragma unroll
                    for (int r = 0; r < 4; ++r) {
                        float p = EXP2(s[c][r] - 12.f);
                        if (diag && (kt * 64 + c * 16 + q4 * 4 + r > qrow)) p = 0.f;
                        lsum += p;
                        bf16 ph = (bf16)p;
                        pb4[c][r] = *(const short*)&ph;
                    }
                l_r[g] += lsum;
                // O^T += V^T P^T
#pragma unroll
                for (int nc = 0; nc < 4; ++nc)
#pragma unroll
                    for (int c = 0; c < 4; ++c)
                        o_acc[g][nc] = __builtin_amdgcn_mfma_f32_16x16x16bf16_1k(
                            vf[nc][c], pb4[c], o_acc[g][nc], 0, 0, 0);
            }
            __syncthreads();
        }

        // ---- epilogue: reduce l across q4 sub-lanes, normalize, store ----
#pragma unroll
        for (int g = 0; g < 4; ++g) {
            float l = l_r[g];
            l += __shfl_xor(l, 16, 64);
            l += __shfl_xor(l, 32, 64);
            float inv = 1.f / l;
            int qrow = qtile * 64 + g * 16 + l16;
            bf16* op = O + (size_t)(b * Ln + qrow) * (Hn * HDn) + h * 64;
#pragma unroll
            for (int nc = 0; nc < 4; ++nc) {
                bf16x4 o;
#pragma unroll
                for (int r = 0; r < 4; ++r) o[r] = (bf16)(o_acc[g][nc][r] * inv);
                *(bf16x4*)(op + nc * 16 + q4 * 4) = o;
            }
        }
    }
}

// ---------------- launch ----------------
extern "C" void kernel_launch(void* const* d_in, const int* in_sizes, int n_in,
                              void* d_out, int out_size, void* d_ws, size_t ws_size,
                              hipStream_t stream) {
    const float* x  = (const float*)d_in[0];
    const float* fc = (const float*)d_in[1];
    const float* wq = (const float*)d_in[2];
    const float* wk = (const float*)d_in[3];
    const float* wv = (const float*)d_in[4];
    const float* wo = (const float*)d_in[5];
    float* out = (float*)d_out;

    const size_t T = (size_t)Bn * Ln;  // 4096 tokens
    char* p = (char*)d_ws;
    bf16* xb    = (bf16*)p; p += T * DIMn * 2;
    bf16* wqkvb = (bf16*)p; p += (size_t)TS * DIMn * 2;
    bf16* wob   = (bf16*)p; p += (size_t)DIMn * Hn * HDn * 2;
    bf16* qkv   = (bf16*)p; p += T * TS * 2;
    bf16* ao    = (bf16*)p; p += T * Hn * HDn * 2;

    // one fused cast kernel: 18,874,368 elems / 4 per thread
    cast_all<<<dim3(18432), dim3(256), 0, stream>>>(x, wq, wk, wv, wo, xb, wqkvb, wob);

    // fused QKV projection: [4096, 3072]
    gemm_bt<true><<<dim3(TS / 128, 32), dim3(256), 0, stream>>>(xb, wqkvb, qkv, 4096, TS, 2048);

    // attention (Q/K rope fused inside)
    attn_kernel<<<dim3(16, KVn, Bn), dim3(256), 0, stream>>>(qkv, fc, ao);

    gemm_bt<false><<<dim3(16, 32), dim3(256), 0, stream>>>(ao, wob, out, 4096, 2048, 2048);
}

// Round 5
// 307.515 us; speedup vs baseline: 1.9451x; 1.0640x over previous
//
#include <hip/hip_runtime.h>
#include <stdint.h>

typedef __bf16 bf16;
typedef __attribute__((ext_vector_type(8))) __bf16 bf16x8;
typedef __attribute__((ext_vector_type(4))) __bf16 bf16x4;
typedef __attribute__((ext_vector_type(4))) short short4v;
typedef __attribute__((ext_vector_type(4))) float f32x4;

static constexpr int Bn = 2, Ln = 2048, DIMn = 2048, Hn = 32, KVn = 8, HDn = 64;
static constexpr int TS = 3072;  // fused qkv token stride (2048 q + 512 k + 512 v)

#if defined(__has_builtin)
#if __has_builtin(__builtin_amdgcn_exp2f)
#define EXP2(x) __builtin_amdgcn_exp2f(x)
#endif
#endif
#ifndef EXP2
#define EXP2(x) exp2f(x)
#endif

#define TO_LDS(p) ((__attribute__((address_space(3))) uint32_t*)(uintptr_t)(p))
#define TO_GLB(p) ((const __attribute__((address_space(1))) uint32_t*)(uintptr_t)(p))

// ---------------- fused cast fp32 -> bf16 for all 5 inputs ----------------
__global__ void cast_all(const float* __restrict__ x, const float* __restrict__ wq,
                         const float* __restrict__ wk, const float* __restrict__ wv,
                         const float* __restrict__ wo, bf16* __restrict__ xb,
                         bf16* __restrict__ wqkvb, bf16* __restrict__ wob) {
    size_t i = (size_t)(blockIdx.x * blockDim.x + threadIdx.x) * 4;
    const float* src;
    bf16* dst;
    if (i < 8388608) {
        src = x + i; dst = xb + i;
    } else if (i < 8388608 + 6291456) {
        size_t j = i - 8388608;
        dst = wqkvb + j;
        if (j < 4194304)      src = wq + j;
        else if (j < 5242880) src = wk + (j - 4194304);
        else                  src = wv + (j - 5242880);
    } else {
        size_t j = i - 14680064;
        src = wo + j; dst = wob + j;
    }
    float4 v = *(const float4*)src;
    bf16 o[4] = {(bf16)v.x, (bf16)v.y, (bf16)v.z, (bf16)v.w};
    *(uint64_t*)dst = *(uint64_t*)o;
}

// ---------------- RoPE in-place on K region of qkv (cols 2048..2559) ----------------
__global__ void rope_k(bf16* __restrict__ qkv, const float* __restrict__ fc) {
    int idx = blockIdx.x * blockDim.x + threadIdx.x;   // T * 8 * 32 = 1,048,576
    int i   = idx & 31;
    int kvh = (idx >> 5) & 7;
    int bl  = idx >> 8;
    int l   = bl & (Ln - 1);
    size_t base = (size_t)bl * TS + 2048 + kvh * 64 + 2 * i;
    float cr = fc[l * 32 + i];
    float sr = fc[65536 + l * 32 + i];
    float x0 = (float)qkv[base], x1 = (float)qkv[base + 1];
    qkv[base]     = (bf16)(x0 * cr - x1 * sr);
    qkv[base + 1] = (bf16)(x0 * sr + x1 * cr);
}

// ---------------- GEMM: C[M,N] = A[M,K] * B[N,K]^T  (bf16 in, fp32 acc) ----------------
template <bool OUT_BF16>
__global__ __launch_bounds__(256) void gemm_bt(const bf16* __restrict__ A,
                                               const bf16* __restrict__ Bm,
                                               void* __restrict__ C,
                                               int M, int N, int K) {
    __shared__ bf16 sA[128 * 32];
    __shared__ bf16 sB[128 * 32];
    const int t    = threadIdx.x;
    const int wave = t >> 6, lane = t & 63;
    const int q4 = lane >> 4, l16 = lane & 15;
    const int bm = blockIdx.y * 128, bn = blockIdx.x * 128;
    const int wm = (wave >> 1) * 64, wn = (wave & 1) * 64;

    f32x4 acc[4][4] = {};

    const int srow = wave * 16 + (lane >> 2);
    const int scol = (lane & 3) * 8;
    const bf16* pa = A + (size_t)(bm + srow) * K + scol;
    const bf16* pb = Bm + (size_t)(bn + srow) * K + scol;
    bf16* la = &sA[wave * 16 * 32];
    bf16* lb = &sB[wave * 16 * 32];

    for (int k0 = 0; k0 < K; k0 += 32) {
#pragma unroll
        for (int p = 0; p < 2; ++p) {
            __builtin_amdgcn_global_load_lds(TO_GLB(pa + (size_t)p * 64 * K),
                                             TO_LDS(la + p * 64 * 32), 16, 0, 0);
            __builtin_amdgcn_global_load_lds(TO_GLB(pb + (size_t)p * 64 * K),
                                             TO_LDS(lb + p * 64 * 32), 16, 0, 0);
        }
        pa += 32; pb += 32;
        __syncthreads();
        bf16x8 af[4], bfr[4];
#pragma unroll
        for (int i = 0; i < 4; ++i) {
            af[i]  = *(const bf16x8*)(&sA[(wm + i * 16 + l16) * 32 + q4 * 8]);
            bfr[i] = *(const bf16x8*)(&sB[(wn + i * 16 + l16) * 32 + q4 * 8]);
        }
#pragma unroll
        for (int mi = 0; mi < 4; ++mi)
#pragma unroll
            for (int ni = 0; ni < 4; ++ni)
                acc[mi][ni] = __builtin_amdgcn_mfma_f32_16x16x32_bf16(af[mi], bfr[ni],
                                                                      acc[mi][ni], 0, 0, 0);
        __syncthreads();
    }

#pragma unroll
    for (int mi = 0; mi < 4; ++mi)
#pragma unroll
        for (int ni = 0; ni < 4; ++ni)
#pragma unroll
            for (int r = 0; r < 4; ++r) {
                size_t row = bm + wm + mi * 16 + q4 * 4 + r;
                size_t col = bn + wn + ni * 16 + l16;
                if (OUT_BF16)
                    ((bf16*)C)[row * N + col] = (bf16)acc[mi][ni][r];
                else
                    ((float*)C)[row * N + col] = acc[mi][ni][r];
            }
}

// ---------------- flash attention: 8 waves = 4 heads x 2 key-halves ----------------
// Block = (pair, kvh, b), 512 threads. Wave w: head kvh*4 + (w&3), key-half kh = w>>2.
// Each wave: all 64 q rows of its head, keys [kh*32, kh*32+32) of each 64-key tile.
// Uniform q-tile pairs (31-pair, pair): 33 tile-iters. Static-max softmax in log2
// domain (scale*log2e folded into Q in-register RoPE): p = exp2(s-12), l deferred.
// kh=1 partials combined into kh=0 via LDS once per q-tile. K pre-roped globally.
__global__ __launch_bounds__(512, 1) void attn_kernel(const bf16* __restrict__ QKV,
                                                      const float* __restrict__ fc,
                                                      bf16* __restrict__ O) {
    constexpr int LDK = 72;
    __shared__ bf16 sK[64 * LDK];          // [key][hd]
    __shared__ bf16 sV[64 * LDK];          // transposed: [hd][key]
    __shared__ float sComb[4][64][68];     // o_acc combine: [head][lane][g*16+nc*4+r]
    __shared__ float sL[4][64][4];         // l combine
    const int t    = threadIdx.x;
    const int wave = t >> 6, lane = t & 63;
    const int q4 = lane >> 4, l16 = lane & 15;
    const int hidx = wave & 3, kh = wave >> 2;
    const int pair = blockIdx.x, kvh = blockIdx.y, b = blockIdx.z;
    const int h = kvh * 4 + hidx;
    const int c0 = kh * 2;                 // this wave's key chunks: c0, c0+1
    constexpr float SC = 0.125f * 1.44269504088896340736f;

    const bf16* kb = QKV + (size_t)(b * Ln) * TS + 2048 + kvh * 64;
    const bf16* vb = kb + 512;
    // staging maps (512 threads)
    const int krow = t >> 3;               // 0..63
    const int kc8  = (t & 7) * 8;
    const int vkey = t & 63, vhd0 = (t >> 6) * 8;

    for (int half = 0; half < 2; ++half) {
        const int qtile = half == 0 ? 31 - pair : pair;

        // ---- load Q fragments, RoPE + scale in-register ----
        bf16x8 qf[4][2];
#pragma unroll
        for (int g = 0; g < 4; ++g) {
            int ql = qtile * 64 + g * 16 + l16;
            const bf16* qp = QKV + (size_t)(b * Ln + ql) * TS + h * 64;
#pragma unroll
            for (int hc = 0; hc < 2; ++hc) {
                bf16x8 raw = *(const bf16x8*)(qp + hc * 32 + q4 * 8);
                float4 c4 = *(const float4*)(fc + ql * 32 + hc * 16 + q4 * 4);
                float4 s4 = *(const float4*)(fc + 65536 + ql * 32 + hc * 16 + q4 * 4);
                bf16x8 o;
#pragma unroll
                for (int m = 0; m < 4; ++m) {
                    float cr = ((const float*)&c4)[m], sr = ((const float*)&s4)[m];
                    float x0 = (float)raw[2 * m], x1 = (float)raw[2 * m + 1];
                    o[2 * m]     = (bf16)((x0 * cr - x1 * sr) * SC);
                    o[2 * m + 1] = (bf16)((x0 * sr + x1 * cr) * SC);
                }
                qf[g][hc] = o;
            }
        }

        f32x4 o_acc[4][4] = {};
        float l_r[4] = {0.f, 0.f, 0.f, 0.f};

        // ---- prefetch tile 0 ----
        bf16x8 kreg = *(const bf16x8*)(kb + (size_t)krow * TS + kc8);
        bf16x8 vreg = *(const bf16x8*)(vb + (size_t)vkey * TS + vhd0);

        for (int kt = 0; kt <= qtile; ++kt) {
            // ---- write staged tile to LDS ----
            *(float4*)(&sK[krow * LDK + kc8]) = *(float4*)&kreg;
            {
                bf16 vv[8];
                *(bf16x8*)vv = vreg;
#pragma unroll
                for (int j = 0; j < 8; ++j) sV[(vhd0 + j) * LDK + vkey] = vv[j];
            }
            __syncthreads();

            // ---- prefetch next tile ----
            if (kt < qtile) {
                kreg = *(const bf16x8*)(kb + (size_t)((kt + 1) * 64 + krow) * TS + kc8);
                vreg = *(const bf16x8*)(vb + (size_t)((kt + 1) * 64 + vkey) * TS + vhd0);
            }

            // ---- fragments for this wave's key-half (shared across 4 g) ----
            bf16x8 kf[2][2];
#pragma unroll
            for (int ci = 0; ci < 2; ++ci)
#pragma unroll
                for (int hc = 0; hc < 2; ++hc)
                    kf[ci][hc] = *(const bf16x8*)(&sK[((c0 + ci) * 16 + l16) * LDK + hc * 32 + q4 * 8]);
            short4v vf[4][2];
#pragma unroll
            for (int nc = 0; nc < 4; ++nc)
#pragma unroll
                for (int ci = 0; ci < 2; ++ci)
                    vf[nc][ci] = *(const short4v*)(&sV[(nc * 16 + l16) * LDK + (c0 + ci) * 16 + q4 * 4]);

            const bool diag = (kt == qtile);
#pragma unroll
            for (int g = 0; g < 4; ++g) {
                f32x4 s[2];
#pragma unroll
                for (int ci = 0; ci < 2; ++ci) {
                    f32x4 a = {};
                    a = __builtin_amdgcn_mfma_f32_16x16x32_bf16(kf[ci][0], qf[g][0], a, 0, 0, 0);
                    a = __builtin_amdgcn_mfma_f32_16x16x32_bf16(kf[ci][1], qf[g][1], a, 0, 0, 0);
                    s[ci] = a;
                }
                int qrow = qtile * 64 + g * 16 + l16;
                float lsum = 0.f;
                short4v pb4[2];
#pragma unroll
                for (int ci = 0; ci < 2; ++ci)
#pragma unroll
                    for (int r = 0; r < 4; ++r) {
                        float p = EXP2(s[ci][r] - 12.f);
                        if (diag && (kt * 64 + (c0 + ci) * 16 + q4 * 4 + r > qrow)) p = 0.f;
                        lsum += p;
                        bf16 ph = (bf16)p;
                        pb4[ci][r] = *(const short*)&ph;
                    }
                l_r[g] += lsum;
#pragma unroll
                for (int nc = 0; nc < 4; ++nc)
#pragma unroll
                    for (int ci = 0; ci < 2; ++ci)
                        o_acc[g][nc] = __builtin_amdgcn_mfma_f32_16x16x16bf16_1k(
                            vf[nc][ci], pb4[ci], o_acc[g][nc], 0, 0, 0);
            }
            __syncthreads();
        }

        // ---- combine kh=1 partials into kh=0 ----
        if (kh) {
#pragma unroll
            for (int g = 0; g < 4; ++g) {
#pragma unroll
                for (int nc = 0; nc < 4; ++nc)
                    *(f32x4*)(&sComb[hidx][lane][g * 16 + nc * 4]) = o_acc[g][nc];
                sL[hidx][lane][g] = l_r[g];
            }
        }
        __syncthreads();
        if (!kh) {
#pragma unroll
            for (int g = 0; g < 4; ++g) {
                l_r[g] += sL[hidx][lane][g];
#pragma unroll
                for (int nc = 0; nc < 4; ++nc)
                    o_acc[g][nc] += *(const f32x4*)(&sComb[hidx][lane][g * 16 + nc * 4]);
            }
            // ---- epilogue: reduce l across q4 sub-lanes, normalize, store ----
#pragma unroll
            for (int g = 0; g < 4; ++g) {
                float l = l_r[g];
                l += __shfl_xor(l, 16, 64);
                l += __shfl_xor(l, 32, 64);
                float inv = 1.f / l;
                int qrow = qtile * 64 + g * 16 + l16;
                bf16* op = O + (size_t)(b * Ln + qrow) * (Hn * HDn) + h * 64;
#pragma unroll
                for (int nc = 0; nc < 4; ++nc) {
                    bf16x4 o;
#pragma unroll
                    for (int r = 0; r < 4; ++r) o[r] = (bf16)(o_acc[g][nc][r] * inv);
                    *(bf16x4*)(op + nc * 16 + q4 * 4) = o;
                }
            }
        }
        __syncthreads();
    }
}

// ---------------- launch ----------------
extern "C" void kernel_launch(void* const* d_in, const int* in_sizes, int n_in,
                              void* d_out, int out_size, void* d_ws, size_t ws_size,
                              hipStream_t stream) {
    const float* x  = (const float*)d_in[0];
    const float* fc = (const float*)d_in[1];
    const float* wq = (const float*)d_in[2];
    const float* wk = (const float*)d_in[3];
    const float* wv = (const float*)d_in[4];
    const float* wo = (const float*)d_in[5];
    float* out = (float*)d_out;

    const size_t T = (size_t)Bn * Ln;  // 4096 tokens
    char* p = (char*)d_ws;
    bf16* xb    = (bf16*)p; p += T * DIMn * 2;
    bf16* wqkvb = (bf16*)p; p += (size_t)TS * DIMn * 2;
    bf16* wob   = (bf16*)p; p += (size_t)DIMn * Hn * HDn * 2;
    bf16* qkv   = (bf16*)p; p += T * TS * 2;
    bf16* ao    = (bf16*)p; p += T * Hn * HDn * 2;

    cast_all<<<dim3(18432), dim3(256), 0, stream>>>(x, wq, wk, wv, wo, xb, wqkvb, wob);

    // fused QKV projection: [4096, 3072]
    gemm_bt<true><<<dim3(TS / 128, 32), dim3(256), 0, stream>>>(xb, wqkvb, qkv, 4096, TS, 2048);

    // pre-rope K region (Q roped in-register inside attn)
    rope_k<<<dim3(4096), dim3(256), 0, stream>>>(qkv, fc);

    attn_kernel<<<dim3(16, KVn, Bn), dim3(512), 0, stream>>>(qkv, fc, ao);

    gemm_bt<false><<<dim3(16, 32), dim3(256), 0, stream>>>(ao, wob, out, 4096, 2048, 2048);
}